// Round 3
// baseline (86.065 us; speedup 1.0000x reference)
//
#include <hip/hip_runtime.h>

#define MARGIN 0.2f
#define BATCH 512
#define FEAT 256
#define NF4 (FEAT / 4)   // 64 float4 per row

// ---------------------------------------------------------------------------
// One block per anchor i (512 threads, thread j owns column j).
//  1. stage x_i in LDS (float4, broadcast-read later -> conflict-free)
//  2. d(i,j) = sum_f (x_i[f]-x_j[f])^2 ; x_j read as float4 (L1/L2 resident)
//  3. ballot-compact positives/negatives into LDS lists (2 LDS atomics/wave,
//     not 512/block like round 0)
//  4. dense cp*cn hinge loop (~4K terms over 512 threads)
//  5. block reduce -> partial[i] = (hinge_sum, cp*cn). Every slot is fully
//     written every call, so the 0xAA re-poison of d_ws needs no zero-init.
// ---------------------------------------------------------------------------
__global__ __launch_bounds__(512) void anchor_kernel(const float* __restrict__ X,
                                                     const int* __restrict__ y,
                                                     float2* __restrict__ partial) {
    __shared__ float4 xi_s[NF4];
    __shared__ float  pos_s[BATCH];
    __shared__ float  neg_s[BATCH];
    __shared__ int    cnt_s[2];
    __shared__ float  wsum[8];

    const int i   = blockIdx.x;
    const int tid = threadIdx.x;
    const float4* X4 = (const float4*)X;

    if (tid < NF4) xi_s[tid] = X4[i * NF4 + tid];
    if (tid < 2)   cnt_s[tid] = 0;
    __syncthreads();

    // --- squared distance d(i, j=tid) ---
    float s = 0.f;
    {
        const float4* xj = X4 + (size_t)tid * NF4;
#pragma unroll 4
        for (int f = 0; f < NF4; ++f) {
            float4 a = xi_s[f];   // LDS broadcast
            float4 b = xj[f];     // own row, sequential 16B -> L1 line reuse
            float d0 = a.x - b.x, d1 = a.y - b.y;
            float d2 = a.z - b.z, d3 = a.w - b.w;
            s = fmaf(d0, d0, s); s = fmaf(d1, d1, s);
            s = fmaf(d2, d2, s); s = fmaf(d3, d3, s);
        }
    }

    const int yi = y[i];
    const int yj = y[tid];
    const bool is_pos = (yj == yi) && (tid != i);
    const bool is_neg = (yj != yi);

    // --- ballot-based compaction (order in the lists is irrelevant) ---
    const int lane = tid & 63;
    const unsigned long long lt = (((unsigned long long)1) << lane) - 1;
    unsigned long long mp = __ballot(is_pos);
    unsigned long long mn = __ballot(is_neg);
    int basep = 0, basen = 0;
    if (lane == 0) {
        basep = atomicAdd(&cnt_s[0], __popcll(mp));
        basen = atomicAdd(&cnt_s[1], __popcll(mn));
    }
    basep = __shfl(basep, 0);
    basen = __shfl(basen, 0);
    if (is_pos) pos_s[basep + __popcll(mp & lt)] = s + MARGIN;
    if (is_neg) neg_s[basen + __popcll(mn & lt)] = s;
    __syncthreads();

    const int cp = cnt_s[0], cn = cnt_s[1];

    // --- dense hinge: sum_{j in pos} sum_{k in neg} max(dp - dn, 0) ---
    float hs = 0.f;
    for (int jj = 0; jj < cp; ++jj) {          // ~8 iterations, uniform
        float dp = pos_s[jj];                  // LDS broadcast
        for (int k = tid; k < cn; k += 512)    // consecutive -> conflict-free
            hs += fmaxf(dp - neg_s[k], 0.f);
    }

    // --- block reduction: wave shuffle + LDS across 8 waves ---
#pragma unroll
    for (int off = 32; off > 0; off >>= 1) hs += __shfl_down(hs, off);
    if (lane == 0) wsum[tid >> 6] = hs;
    __syncthreads();
    if (tid == 0) {
        float bs = 0.f;
#pragma unroll
        for (int w = 0; w < 8; ++w) bs += wsum[w];
        partial[i] = make_float2(bs, (float)(cp * cn));  // exact: cp*cn < 2^24
    }
}

// ---------------------------------------------------------------------------
// Single-block final reduction over 512 (sum, count) pairs + divide.
// ---------------------------------------------------------------------------
__global__ __launch_bounds__(512) void reduce_kernel(const float2* __restrict__ partial,
                                                     float* __restrict__ out) {
    __shared__ float ws[8], wc[8];
    const int tid = threadIdx.x;
    float2 v = partial[tid];
    float s = v.x, c = v.y;
#pragma unroll
    for (int off = 32; off > 0; off >>= 1) {
        s += __shfl_down(s, off);
        c += __shfl_down(c, off);
    }
    if ((tid & 63) == 0) { ws[tid >> 6] = s; wc[tid >> 6] = c; }
    __syncthreads();
    if (tid == 0) {
        float st = 0.f, ct = 0.f;
#pragma unroll
        for (int w = 0; w < 8; ++w) { st += ws[w]; ct += wc[w]; }
        out[0] = st / ct;
    }
}

extern "C" void kernel_launch(void* const* d_in, const int* in_sizes, int n_in,
                              void* d_out, int out_size, void* d_ws, size_t ws_size,
                              hipStream_t stream) {
    const float* X = (const float*)d_in[0];   // [512, 256] fp32
    const int*   y = (const int*)d_in[1];     // [512] labels
    float* out = (float*)d_out;               // scalar fp32
    float2* partial = (float2*)d_ws;          // 512 float2 = 4 KB

    anchor_kernel<<<BATCH, 512, 0, stream>>>(X, y, partial);
    reduce_kernel<<<1, 512, 0, stream>>>(partial, out);
}